// Round 1
// baseline (705.699 us; speedup 1.0000x reference)
//
#include <hip/hip_runtime.h>
#include <cstdint>
#include <cstddef>

#define H2 1024
#define TT 512
#define NSTEPS 64
#define RBLK 32   // recurrence blocks
#define RTHR 512  // threads per recurrence block

using floatx4 = __attribute__((__ext_vector_type__(4))) float;
using half8   = __attribute__((__ext_vector_type__(8))) _Float16;
using half4   = __attribute__((__ext_vector_type__(4))) _Float16;
typedef unsigned long long u64;

__device__ __forceinline__ float tanh_fast(float x) {
  return 1.0f - 2.0f / (__expf(2.0f * x) + 1.0f);
}

#define GLDS16(gp, lp)                                                         \
  __builtin_amdgcn_global_load_lds(                                            \
      (const __attribute__((address_space(1))) void*)(gp),                     \
      (__attribute__((address_space(3))) void*)(lp), 16, 0, 0)

// ---------------------------------------------------------------------------
// Wait-free dataflow recurrence (no barrier, no counter, no LDS).
// vbuf is pre-poisoned with 0xFFFFFFFF; producers publish y_i values as
// 8-byte agent-scope atomic stores (pairs, so no tearing), consumers poll the
// data words directly until non-poison. A finite FMA result can never be the
// all-ones bit pattern (full-payload -NaN), so data-as-flag is safe.
//
// Partitioning: 32 blocks x 8 waves; wave owns 4 rows (r0..r0+3); lane l owns
// columns {256*j + 4*l + c : j<4, c<4} -> each wave covers all 1024 columns
// exactly once. Therefore each wave computes ||y_{i-1}||^2 from the 16 values
// its lanes loaded anyway (6 shuffles), with NO cross-wave communication:
// waves free-run, zero __syncthreads in the step loop.
// W fragment (64 floats/lane) is loaded ONCE into VGPRs and held all kernel.
// ---------------------------------------------------------------------------
__device__ __forceinline__ void poll_z(const float* buf, int l, float z[16]) {
  const u64* src = (const u64*)buf + 2 * l;
  for (;;) {
    u64 v[8];
#pragma unroll
    for (int j = 0; j < 4; ++j) {
#pragma unroll
      for (int q = 0; q < 2; ++q)
        v[2 * j + q] = __hip_atomic_load(src + 128 * j + q, __ATOMIC_RELAXED,
                                         __HIP_MEMORY_SCOPE_AGENT);
    }
    bool ok = true;
#pragma unroll
    for (int j = 0; j < 8; ++j) ok &= (v[j] != ~0ull);
    if (__all(ok)) {
#pragma unroll
      for (int j = 0; j < 8; ++j) {
        z[2 * j] = __builtin_bit_cast(float, (unsigned)(v[j] & 0xFFFFFFFFu));
        z[2 * j + 1] = __builtin_bit_cast(float, (unsigned)(v[j] >> 32));
      }
      return;
    }
    __builtin_amdgcn_s_sleep(2);
  }
}

__global__ __launch_bounds__(RTHR, 1) void recur_kernel(
    const float* __restrict__ W, const float* __restrict__ bias,
    const float* __restrict__ u0, float* __restrict__ vbuf,
    float* __restrict__ norm2) {
  int tid = threadIdx.x;
  int w = tid >> 6, l = tid & 63;
  int r0 = blockIdx.x * RBLK + w * 4;  // this wave's 4 rows

  // W held in VGPRs for the whole kernel: wreg[p][j] = W[r0+p][256j+4l .. +3]
  float4 wreg[4][4];
  float bl[4];
#pragma unroll
  for (int p = 0; p < 4; ++p) {
    const float* wr = W + ((size_t)(r0 + p) << 10) + 4 * l;
#pragma unroll
    for (int j = 0; j < 4; ++j) wreg[p][j] = *(const float4*)(wr + 256 * j);
    bl[p] = bias[r0 + p];
  }

  float z[16];
  for (int i = 0; i < NSTEPS; ++i) {
    if (i == 0) {
      const float* u = u0 + 4 * l;
#pragma unroll
      for (int j = 0; j < 4; ++j)
#pragma unroll
        for (int c = 0; c < 4; ++c) z[4 * j + c] = u[256 * j + c];
    } else {
      poll_z(vbuf + ((size_t)(i - 1) << 10), l, z);
    }

    // ||y_{i-1}||^2 : this wave's lanes cover all 1024 columns exactly once
    float sq = 0.f;
#pragma unroll
    for (int j = 0; j < 16; ++j) sq += z[j] * z[j];
#pragma unroll
    for (int off = 1; off <= 32; off <<= 1) sq += __shfl_xor(sq, off, 64);
    float rs = (i == 0) ? 1.0f : 1.0f / fmaxf(sqrtf(sq), 1e-12f);
    if (i > 0 && blockIdx.x == 0 && tid == 0) norm2[i - 1] = sq;

    // dot(W_row, y_{i-1}) for 4 rows, column-split across the wave
    float acc[4];
#pragma unroll
    for (int p = 0; p < 4; ++p) {
      float a = 0.f;
#pragma unroll
      for (int j = 0; j < 4; ++j) {
        float4 wv = wreg[p][j];
        a += wv.x * z[4 * j] + wv.y * z[4 * j + 1] + wv.z * z[4 * j + 2] +
             wv.w * z[4 * j + 3];
      }
      acc[p] = a;
    }
#pragma unroll
    for (int p = 0; p < 4; ++p)
#pragma unroll
      for (int off = 1; off <= 32; off <<= 1)
        acc[p] += __shfl_xor(acc[p], off, 64);

    if (l == 0) {
      float y0 = acc[0] * rs + bl[0], y1 = acc[1] * rs + bl[1];
      float y2 = acc[2] * rs + bl[2], y3 = acc[3] * rs + bl[3];
      u64 a01 = ((u64)__builtin_bit_cast(unsigned, y1) << 32) |
                (u64)__builtin_bit_cast(unsigned, y0);
      u64 a23 = ((u64)__builtin_bit_cast(unsigned, y3) << 32) |
                (u64)__builtin_bit_cast(unsigned, y2);
      u64* dst = (u64*)(vbuf + ((size_t)i << 10) + r0);
      __hip_atomic_store(dst, a01, __ATOMIC_RELAXED, __HIP_MEMORY_SCOPE_AGENT);
      __hip_atomic_store(dst + 1, a23, __ATOMIC_RELAXED,
                         __HIP_MEMORY_SCOPE_AGENT);
    }
  }

  // tail: ||y_63||^2 for gemm2's epilogue (computed by block 0, wave 0)
  if (blockIdx.x == 0 && w == 0) {
    poll_z(vbuf + ((size_t)(NSTEPS - 1) << 10), l, z);
    float sq = 0.f;
#pragma unroll
    for (int j = 0; j < 16; ++j) sq += z[j] * z[j];
#pragma unroll
    for (int off = 1; off <= 32; off <<= 1) sq += __shfl_xor(sq, off, 64);
    if (l == 0) norm2[NSTEPS - 1] = sq;
  }
}

// ---------------------------------------------------------------------------
// Pre-pass 1: W fp32 -> fp16 row-major
// ---------------------------------------------------------------------------
__global__ __launch_bounds__(256) void wconv_kernel(const float* __restrict__ W,
                                                    _Float16* __restrict__ Wh) {
  int i = blockIdx.x * 256 + threadIdx.x;
  float4 v = ((const float4*)W)[i];
  half4 o = {(_Float16)v.x, (_Float16)v.y, (_Float16)v.z, (_Float16)v.w};
  ((half4*)Wh)[i] = o;
}

// ---------------------------------------------------------------------------
// Pre-pass 2: h (n,d,t) fp32 -> hhT (n,t,d) fp16, 64x64 LDS tile transpose
// ---------------------------------------------------------------------------
__global__ __launch_bounds__(256) void transpose_h(const float* __restrict__ h,
                                                   _Float16* __restrict__ hhT) {
  int n = blockIdx.z, d0 = blockIdx.x * 64, t0 = blockIdx.y * 64;
  __shared__ float tile[64][65];
  const float* hb = h + ((size_t)n * H2 + d0) * TT + t0;
  int dr = threadIdx.x >> 4, tc = (threadIdx.x & 15) << 2;
#pragma unroll
  for (int p = 0; p < 4; ++p) {
    float4 v = *(const float4*)(hb + (size_t)(dr + p * 16) * TT + tc);
    tile[dr + p * 16][tc] = v.x;
    tile[dr + p * 16][tc + 1] = v.y;
    tile[dr + p * 16][tc + 2] = v.z;
    tile[dr + p * 16][tc + 3] = v.w;
  }
  __syncthreads();
  _Float16* ob = hhT + ((size_t)n * TT + t0) * H2 + d0;
  int tr = threadIdx.x >> 3, seg = threadIdx.x & 7;
#pragma unroll
  for (int p = 0; p < 2; ++p) {
    int t = tr + p * 32;
    half8 hv;
#pragma unroll
    for (int u = 0; u < 8; ++u) hv[u] = (_Float16)tile[seg * 8 + u][t];
    *(half8*)(ob + (size_t)t * H2 + seg * 8) = hv;
  }
}

// ---------------------------------------------------------------------------
// GEMM from pre-converted fp16 operands, global_load_lds staging.
// C[e,t] = sum_d Wh[e,d]*hhT[n,t,d]; epilogue tanh + u_ws dot -> scores atomics
// ---------------------------------------------------------------------------
__global__ __launch_bounds__(256) void gemm2(
    const _Float16* __restrict__ Wh, const _Float16* __restrict__ hhT,
    const float* __restrict__ bias, const float* __restrict__ vbuf,
    const float* __restrict__ norm2, float* __restrict__ scores) {
  int x = blockIdx.x;
  int xcd = x & 7, slot = x >> 3;
  int e_t = slot & 7;
  int tn = xcd * 32 + (slot >> 3);
  int t_t = tn & 3, n = tn >> 2;
  int e_base = e_t * 128, t_base = t_t * 128;

  int tid = threadIdx.x, lane = tid & 63, w = tid >> 6;
  int q = lane >> 4, m = lane & 15;
  int eoff = (w & 1) * 64, toff = (w >> 1) * 64;

  __shared__ __align__(16) _Float16 Ash[128 * 32];
  __shared__ __align__(16) _Float16 Bsh[128 * 32];

  floatx4 zero = {0.f, 0.f, 0.f, 0.f};
  floatx4 acc[4][4];
#pragma unroll
  for (int i = 0; i < 4; ++i)
#pragma unroll
    for (int j = 0; j < 4; ++j) acc[i][j] = zero;

  int rl = lane >> 2, kseg = lane & 3;
  const _Float16* gA0 =
      Wh + (((size_t)(e_base + w * 32 + rl)) << 10) + kseg * 8;
  const _Float16* gA1 = gA0 + ((size_t)16 << 10);
  const _Float16* gB0 = hhT + ((size_t)n << 19) +
                        (((size_t)(t_base + w * 32 + rl)) << 10) + kseg * 8;
  const _Float16* gB1 = gB0 + ((size_t)16 << 10);
  _Float16* lA0 = Ash + (w * 32) * 32;
  _Float16* lA1 = lA0 + 16 * 32;
  _Float16* lB0 = Bsh + (w * 32) * 32;
  _Float16* lB1 = lB0 + 16 * 32;

  for (int k0 = 0; k0 < H2; k0 += 32) {
    GLDS16(gA0 + k0, lA0);
    GLDS16(gA1 + k0, lA1);
    GLDS16(gB0 + k0, lB0);
    GLDS16(gB1 + k0, lB1);
    __syncthreads();

    half8 af[4], bf[4];
#pragma unroll
    for (int i = 0; i < 4; ++i)
      af[i] = *(const half8*)&Ash[(eoff + i * 16 + m) * 32 + q * 8];
#pragma unroll
    for (int j = 0; j < 4; ++j)
      bf[j] = *(const half8*)&Bsh[(toff + j * 16 + m) * 32 + q * 8];
#pragma unroll
    for (int i = 0; i < 4; ++i)
#pragma unroll
      for (int j = 0; j < 4; ++j)
        acc[i][j] =
            __builtin_amdgcn_mfma_f32_16x16x32_f16(af[i], bf[j], acc[i][j], 0, 0, 0);
    __syncthreads();
  }

  float* uloc = (float*)Ash;
  float* bloc = uloc + 128;
  if (tid < 128) {
    float rsn = 1.0f / fmaxf(sqrtf(norm2[n]), 1e-12f);
    uloc[tid] = vbuf[((size_t)n << 10) + e_base + tid] * rsn;
    bloc[tid] = bias[e_base + tid];
  }
  __syncthreads();

  float part[4] = {0.f, 0.f, 0.f, 0.f};
#pragma unroll
  for (int i = 0; i < 4; ++i) {
#pragma unroll
    for (int reg = 0; reg < 4; ++reg) {
      int el = eoff + i * 16 + q * 4 + reg;
      float ubv = uloc[el];
      float bbv = bloc[el];
#pragma unroll
      for (int j = 0; j < 4; ++j) {
        float y = acc[i][j][reg] + bbv;
        part[j] += tanh_fast(y) * ubv;
      }
    }
  }
#pragma unroll
  for (int j = 0; j < 4; ++j) {
    part[j] += __shfl_xor(part[j], 16, 64);
    part[j] += __shfl_xor(part[j], 32, 64);
    if (lane < 16) {
      int t = t_base + toff + j * 16 + lane;
      atomicAdd(&scores[(size_t)n * TT + t], part[j]);
    }
  }
}

// ---------------------------------------------------------------------------
// Fused softmax + weighted sum
// ---------------------------------------------------------------------------
__global__ __launch_bounds__(256) void out_kernel(
    const float* __restrict__ h, const float* __restrict__ scores,
    float* __restrict__ out) {
  int n = blockIdx.y;
  int ds = blockIdx.x;
  int tid = threadIdx.x;
  int w = tid >> 6, lane = tid & 63;

  __shared__ float sa[TT];
  __shared__ float wred[8];

  float s0 = scores[(size_t)n * TT + tid];
  float s1 = scores[(size_t)n * TT + 256 + tid];

  float mx = fmaxf(s0, s1);
#pragma unroll
  for (int off = 32; off >= 1; off >>= 1) mx = fmaxf(mx, __shfl_xor(mx, off, 64));
  if (lane == 0) wred[w] = mx;
  __syncthreads();
  mx = fmaxf(fmaxf(wred[0], wred[1]), fmaxf(wred[2], wred[3]));

  float e0 = __expf(s0 - mx);
  float e1 = __expf(s1 - mx);
  float ssum = e0 + e1;
#pragma unroll
  for (int off = 32; off >= 1; off >>= 1) ssum += __shfl_xor(ssum, off, 64);
  if (lane == 0) wred[4 + w] = ssum;
  __syncthreads();
  ssum = wred[4] + wred[5] + wred[6] + wred[7];
  float inv = 1.0f / ssum;
  sa[tid] = e0 * inv;
  sa[tid + 256] = e1 * inv;
  __syncthreads();

  int d0 = ds * 64 + w * 16;
  const float4* hb = reinterpret_cast<const float4*>(h + (size_t)n * H2 * TT);
#pragma unroll 1
  for (int rr = 0; rr < 16; ++rr) {
    int d = d0 + rr;
    const float4* hr = hb + (size_t)d * (TT / 4);
    float4 a4 = hr[lane];
    float4 b4 = hr[64 + lane];
    int t0 = 4 * lane;
    float acc = a4.x * sa[t0] + a4.y * sa[t0 + 1] + a4.z * sa[t0 + 2] +
                a4.w * sa[t0 + 3] + b4.x * sa[256 + t0] +
                b4.y * sa[256 + t0 + 1] + b4.z * sa[256 + t0 + 2] +
                b4.w * sa[256 + t0 + 3];
#pragma unroll
    for (int off = 1; off <= 32; off <<= 1) acc += __shfl_xor(acc, off, 64);
    if (lane == 0) out[(size_t)n * H2 + d] = acc;
  }
}

// ---------------------------------------------------------------------------
extern "C" void kernel_launch(void* const* d_in, const int* in_sizes, int n_in,
                              void* d_out, int out_size, void* d_ws, size_t ws_size,
                              hipStream_t stream) {
  const float* h    = (const float*)d_in[0];  // (64, 1024, 512)
  const float* W    = (const float*)d_in[1];  // (1024, 1024)
  const float* bias = (const float*)d_in[2];  // (1024,)
  const float* u0   = (const float*)d_in[3];  // (1024,)
  float* out = (float*)d_out;                 // (64, 1024)

  float* wsf    = (float*)d_ws;
  float* norm2  = wsf;                          // 64
  float* scores = wsf + 64;                     // 64*512
  float* vbuf   = wsf + 64 + NSTEPS * TT;       // 64*1024
  unsigned* ctr = (unsigned*)(vbuf + (size_t)NSTEPS * H2);  // legacy pad slot
  float* after_ctr = (float*)(ctr + 16);        // pad
  size_t fixed_floats = (size_t)(after_ctr - wsf);
  _Float16* Wh  = (_Float16*)after_ctr;                       // 1M halfs
  _Float16* hhT = Wh + (size_t)H2 * H2;                       // 32M halfs
  size_t need = fixed_floats * 4 + (size_t)H2 * H2 * 2 +
                (size_t)NSTEPS * TT * H2 * 2;
  bool big = ws_size >= need;

  // zero norm2 + scores (atomically accumulated); poison vbuf for data-polling
  hipMemsetAsync(d_ws, 0, (size_t)(64 + NSTEPS * TT) * sizeof(float), stream);
  hipMemsetAsync(vbuf, 0xFF, (size_t)NSTEPS * H2 * sizeof(float), stream);

  // persistent recurrence, wait-free dataflow sync via poisoned vbuf
  // (cooperative launch only for the co-residency guarantee)
  {
    const float* Wp = W; const float* bp = bias; const float* up = u0;
    float* vp = vbuf; float* np = norm2;
    void* kargs[] = {&Wp, &bp, &up, &vp, &np};
    hipLaunchCooperativeKernel((void*)recur_kernel, dim3(RBLK), dim3(RTHR),
                               kargs, 0, stream);
  }

  if (big) {
    wconv_kernel<<<dim3(H2 * H2 / 1024), dim3(256), 0, stream>>>(W, Wh);
    transpose_h<<<dim3(16, 8, 64), dim3(256), 0, stream>>>(h, hhT);
    gemm2<<<dim3(2048), dim3(256), 0, stream>>>(Wh, hhT, bias, vbuf, norm2,
                                                scores);
  } else {
    gemm2<<<dim3(2048), dim3(256), 0, stream>>>(Wh, hhT, bias, vbuf, norm2,
                                                scores);
  }

  out_kernel<<<dim3(16, 64), dim3(256), 0, stream>>>(h, scores, out);

  (void)in_sizes; (void)n_in; (void)out_size; (void)ws_size;
}

// Round 2
// 507.643 us; speedup vs baseline: 1.3901x; 1.3901x over previous
//
#include <hip/hip_runtime.h>
#include <cstdint>
#include <cstddef>

#define H2 1024
#define TT 512
#define NSTEPS 64
#define RBLK 32   // recurrence blocks
#define RTHR 512  // threads per recurrence block

using floatx4 = __attribute__((__ext_vector_type__(4))) float;
using half8   = __attribute__((__ext_vector_type__(8))) _Float16;
using half4   = __attribute__((__ext_vector_type__(4))) _Float16;
typedef unsigned long long u64;

__device__ __forceinline__ float tanh_fast(float x) {
  return 1.0f - 2.0f / (__expf(2.0f * x) + 1.0f);
}

#define GLDS16(gp, lp)                                                         \
  __builtin_amdgcn_global_load_lds(                                            \
      (const __attribute__((address_space(1))) void*)(gp),                     \
      (__attribute__((address_space(3))) void*)(lp), 16, 0, 0)

// ---------------------------------------------------------------------------
// Recurrence: data-as-flag publication + SINGLE poller wave per block.
//
// vbuf is pre-poisoned 0xFFFFFFFF. Producers (lane g==0 of each 16-lane row
// group) publish y values as 4B agent-scope stores (no vmcnt drain, no flag,
// no counter RMW). In each block, only WAVE 0 polls the previous step's 4KB
// (8 coalesced u64 bypass loads per lane, per-32bit poison checks so any
// tearing granularity is safe), stages it into double-buffered LDS with the
// +4/64 swizzle, and computes ||z||^2 (6-level butterfly). One __syncthreads
// per step releases the other 7 waves; LDS double-buffering removes the
// trailing barrier. This keeps chip-wide poll traffic at 32 waves (R1 had
// 256, whose bypass-load flood queued ahead of the critical publish stores).
//
// W row slice (64 floats/lane) is pinned in VGPRs via opaque empty asm so the
// compiler cannot re-sink the loads into the loop (R0/R1 showed VGPR=52/64 ->
// W was reloaded from L2 every step, on the critical path after detect).
// ---------------------------------------------------------------------------
__global__ __launch_bounds__(RTHR, 1) void recur_kernel(
    const float* __restrict__ W, const float* __restrict__ bias,
    const float* __restrict__ u0, float* __restrict__ vbuf,
    float* __restrict__ norm2) {
  __shared__ __align__(16) float ub[2][H2 + 64];
  __shared__ float bredn[2];
  int tid = threadIdx.x;
  int row = tid >> 4, g = tid & 15;   // 32 rows x 16 lanes
  int r = blockIdx.x * RBLK + row;
  int w = tid >> 6, l = tid & 63;

  // W slice held in VGPRs for the whole kernel, pinned against re-sinking.
  floatx4 wreg[16];
  {
    const floatx4* wr = (const floatx4*)(W + ((size_t)r << 10) + (g << 6));
#pragma unroll
    for (int j = 0; j < 16; ++j) wreg[j] = wr[j];
  }
#pragma unroll
  for (int j = 0; j < 16; ++j) asm volatile("" : "+v"(wreg[j]));
  float bl = bias[r];

  for (int i = 0; i < NSTEPS; ++i) {
    float* cb = ub[i & 1];
    float rs;
    if (i == 0) {
      // stage u0 (raw, rs = 1): all threads, 2 floats each, swizzled
      int f = 2 * tid;
      int addr = f + 4 * (f >> 6);
      float2 v2 = *(const float2*)(u0 + f);
      *(float2*)(cb + addr) = v2;
      __syncthreads();
      rs = 1.0f;
    } else {
      if (w == 0) {
        // poll previous step's data directly (data-as-flag)
        const u64* src = (const u64*)(vbuf + ((size_t)(i - 1) << 10)) + l;
        u64 v[8];
        for (;;) {
          bool ok = true;
#pragma unroll
          for (int j = 0; j < 8; ++j) {
            v[j] = __hip_atomic_load(src + 64 * j, __ATOMIC_RELAXED,
                                     __HIP_MEMORY_SCOPE_AGENT);
            ok &= ((unsigned)(v[j] & 0xFFFFFFFFu) != 0xFFFFFFFFu) &
                  ((unsigned)(v[j] >> 32) != 0xFFFFFFFFu);
          }
          if (__all(ok)) break;
          __builtin_amdgcn_s_sleep(1);
        }
        // stage into swizzled LDS + accumulate norm^2
        float sq = 0.f;
#pragma unroll
        for (int j = 0; j < 8; ++j) {
          int F0 = 2 * l + 128 * j;
          int addr = F0 + 4 * (F0 >> 6);
          *(u64*)(cb + addr) = v[j];
          float f0 = __builtin_bit_cast(float, (unsigned)(v[j] & 0xFFFFFFFFu));
          float f1 = __builtin_bit_cast(float, (unsigned)(v[j] >> 32));
          sq += f0 * f0 + f1 * f1;
        }
#pragma unroll
        for (int off = 1; off <= 32; off <<= 1) sq += __shfl_xor(sq, off, 64);
        if (l == 0) bredn[i & 1] = sq;
      }
      __syncthreads();
      float nrm = bredn[i & 1];
      rs = 1.0f / fmaxf(sqrtf(nrm), 1e-12f);
      if (blockIdx.x == 0 && tid == 64) norm2[i - 1] = nrm;  // off critical wave
    }

    // dot(W_row, z) over this lane's 64-float slice (contiguous in LDS)
    const floatx4* ug = (const floatx4*)(cb + 68 * g);
    float acc = 0.f;
#pragma unroll
    for (int j = 0; j < 16; ++j) {
      floatx4 a = wreg[j], c = ug[j];
      acc += a.x * c.x + a.y * c.y + a.z * c.z + a.w * c.w;
    }
#pragma unroll
    for (int off = 1; off <= 8; off <<= 1) acc += __shfl_xor(acc, off, 64);

    if (g == 0) {
      float yv = acc * rs + bl;
      __hip_atomic_store(vbuf + ((size_t)i << 10) + r, yv, __ATOMIC_RELAXED,
                         __HIP_MEMORY_SCOPE_AGENT);
    }
    // no trailing barrier: ub/bredn are double-buffered, the per-step
    // __syncthreads bounds wave skew to < 1 step.
  }

  // tail: ||y_63||^2 for gemm2's epilogue
  if (blockIdx.x == 0 && w == 0) {
    const u64* src = (const u64*)(vbuf + ((size_t)(NSTEPS - 1) << 10)) + l;
    u64 v[8];
    for (;;) {
      bool ok = true;
#pragma unroll
      for (int j = 0; j < 8; ++j) {
        v[j] = __hip_atomic_load(src + 64 * j, __ATOMIC_RELAXED,
                                 __HIP_MEMORY_SCOPE_AGENT);
        ok &= ((unsigned)(v[j] & 0xFFFFFFFFu) != 0xFFFFFFFFu) &
              ((unsigned)(v[j] >> 32) != 0xFFFFFFFFu);
      }
      if (__all(ok)) break;
      __builtin_amdgcn_s_sleep(1);
    }
    float sq = 0.f;
#pragma unroll
    for (int j = 0; j < 8; ++j) {
      float f0 = __builtin_bit_cast(float, (unsigned)(v[j] & 0xFFFFFFFFu));
      float f1 = __builtin_bit_cast(float, (unsigned)(v[j] >> 32));
      sq += f0 * f0 + f1 * f1;
    }
#pragma unroll
    for (int off = 1; off <= 32; off <<= 1) sq += __shfl_xor(sq, off, 64);
    if (l == 0) norm2[NSTEPS - 1] = sq;
  }
}

// ---------------------------------------------------------------------------
// Pre-pass 1: W fp32 -> fp16 row-major
// ---------------------------------------------------------------------------
__global__ __launch_bounds__(256) void wconv_kernel(const float* __restrict__ W,
                                                    _Float16* __restrict__ Wh) {
  int i = blockIdx.x * 256 + threadIdx.x;
  float4 v = ((const float4*)W)[i];
  half4 o = {(_Float16)v.x, (_Float16)v.y, (_Float16)v.z, (_Float16)v.w};
  ((half4*)Wh)[i] = o;
}

// ---------------------------------------------------------------------------
// Pre-pass 2: h (n,d,t) fp32 -> hhT (n,t,d) fp16, 64x64 LDS tile transpose
// ---------------------------------------------------------------------------
__global__ __launch_bounds__(256) void transpose_h(const float* __restrict__ h,
                                                   _Float16* __restrict__ hhT) {
  int n = blockIdx.z, d0 = blockIdx.x * 64, t0 = blockIdx.y * 64;
  __shared__ float tile[64][65];
  const float* hb = h + ((size_t)n * H2 + d0) * TT + t0;
  int dr = threadIdx.x >> 4, tc = (threadIdx.x & 15) << 2;
#pragma unroll
  for (int p = 0; p < 4; ++p) {
    float4 v = *(const float4*)(hb + (size_t)(dr + p * 16) * TT + tc);
    tile[dr + p * 16][tc] = v.x;
    tile[dr + p * 16][tc + 1] = v.y;
    tile[dr + p * 16][tc + 2] = v.z;
    tile[dr + p * 16][tc + 3] = v.w;
  }
  __syncthreads();
  _Float16* ob = hhT + ((size_t)n * TT + t0) * H2 + d0;
  int tr = threadIdx.x >> 3, seg = threadIdx.x & 7;
#pragma unroll
  for (int p = 0; p < 2; ++p) {
    int t = tr + p * 32;
    half8 hv;
#pragma unroll
    for (int u = 0; u < 8; ++u) hv[u] = (_Float16)tile[seg * 8 + u][t];
    *(half8*)(ob + (size_t)t * H2 + seg * 8) = hv;
  }
}

// ---------------------------------------------------------------------------
// GEMM from pre-converted fp16 operands, global_load_lds staging.
// C[e,t] = sum_d Wh[e,d]*hhT[n,t,d]; epilogue tanh + u_ws dot -> scores atomics
// ---------------------------------------------------------------------------
__global__ __launch_bounds__(256) void gemm2(
    const _Float16* __restrict__ Wh, const _Float16* __restrict__ hhT,
    const float* __restrict__ bias, const float* __restrict__ vbuf,
    const float* __restrict__ norm2, float* __restrict__ scores) {
  int x = blockIdx.x;
  int xcd = x & 7, slot = x >> 3;
  int e_t = slot & 7;
  int tn = xcd * 32 + (slot >> 3);
  int t_t = tn & 3, n = tn >> 2;
  int e_base = e_t * 128, t_base = t_t * 128;

  int tid = threadIdx.x, lane = tid & 63, w = tid >> 6;
  int q = lane >> 4, m = lane & 15;
  int eoff = (w & 1) * 64, toff = (w >> 1) * 64;

  __shared__ __align__(16) _Float16 Ash[128 * 32];
  __shared__ __align__(16) _Float16 Bsh[128 * 32];

  floatx4 zero = {0.f, 0.f, 0.f, 0.f};
  floatx4 acc[4][4];
#pragma unroll
  for (int i = 0; i < 4; ++i)
#pragma unroll
    for (int j = 0; j < 4; ++j) acc[i][j] = zero;

  int rl = lane >> 2, kseg = lane & 3;
  const _Float16* gA0 =
      Wh + (((size_t)(e_base + w * 32 + rl)) << 10) + kseg * 8;
  const _Float16* gA1 = gA0 + ((size_t)16 << 10);
  const _Float16* gB0 = hhT + ((size_t)n << 19) +
                        (((size_t)(t_base + w * 32 + rl)) << 10) + kseg * 8;
  const _Float16* gB1 = gB0 + ((size_t)16 << 10);
  _Float16* lA0 = Ash + (w * 32) * 32;
  _Float16* lA1 = lA0 + 16 * 32;
  _Float16* lB0 = Bsh + (w * 32) * 32;
  _Float16* lB1 = lB0 + 16 * 32;

  for (int k0 = 0; k0 < H2; k0 += 32) {
    GLDS16(gA0 + k0, lA0);
    GLDS16(gA1 + k0, lA1);
    GLDS16(gB0 + k0, lB0);
    GLDS16(gB1 + k0, lB1);
    __syncthreads();

    half8 af[4], bf[4];
#pragma unroll
    for (int i = 0; i < 4; ++i)
      af[i] = *(const half8*)&Ash[(eoff + i * 16 + m) * 32 + q * 8];
#pragma unroll
    for (int j = 0; j < 4; ++j)
      bf[j] = *(const half8*)&Bsh[(toff + j * 16 + m) * 32 + q * 8];
#pragma unroll
    for (int i = 0; i < 4; ++i)
#pragma unroll
      for (int j = 0; j < 4; ++j)
        acc[i][j] =
            __builtin_amdgcn_mfma_f32_16x16x32_f16(af[i], bf[j], acc[i][j], 0, 0, 0);
    __syncthreads();
  }

  float* uloc = (float*)Ash;
  float* bloc = uloc + 128;
  if (tid < 128) {
    float rsn = 1.0f / fmaxf(sqrtf(norm2[n]), 1e-12f);
    uloc[tid] = vbuf[((size_t)n << 10) + e_base + tid] * rsn;
    bloc[tid] = bias[e_base + tid];
  }
  __syncthreads();

  float part[4] = {0.f, 0.f, 0.f, 0.f};
#pragma unroll
  for (int i = 0; i < 4; ++i) {
#pragma unroll
    for (int reg = 0; reg < 4; ++reg) {
      int el = eoff + i * 16 + q * 4 + reg;
      float ubv = uloc[el];
      float bbv = bloc[el];
#pragma unroll
      for (int j = 0; j < 4; ++j) {
        float y = acc[i][j][reg] + bbv;
        part[j] += tanh_fast(y) * ubv;
      }
    }
  }
#pragma unroll
  for (int j = 0; j < 4; ++j) {
    part[j] += __shfl_xor(part[j], 16, 64);
    part[j] += __shfl_xor(part[j], 32, 64);
    if (lane < 16) {
      int t = t_base + toff + j * 16 + lane;
      atomicAdd(&scores[(size_t)n * TT + t], part[j]);
    }
  }
}

// ---------------------------------------------------------------------------
// Fused softmax + weighted sum
// ---------------------------------------------------------------------------
__global__ __launch_bounds__(256) void out_kernel(
    const float* __restrict__ h, const float* __restrict__ scores,
    float* __restrict__ out) {
  int n = blockIdx.y;
  int ds = blockIdx.x;
  int tid = threadIdx.x;
  int w = tid >> 6, lane = tid & 63;

  __shared__ float sa[TT];
  __shared__ float wred[8];

  float s0 = scores[(size_t)n * TT + tid];
  float s1 = scores[(size_t)n * TT + 256 + tid];

  float mx = fmaxf(s0, s1);
#pragma unroll
  for (int off = 32; off >= 1; off >>= 1) mx = fmaxf(mx, __shfl_xor(mx, off, 64));
  if (lane == 0) wred[w] = mx;
  __syncthreads();
  mx = fmaxf(fmaxf(wred[0], wred[1]), fmaxf(wred[2], wred[3]));

  float e0 = __expf(s0 - mx);
  float e1 = __expf(s1 - mx);
  float ssum = e0 + e1;
#pragma unroll
  for (int off = 32; off >= 1; off >>= 1) ssum += __shfl_xor(ssum, off, 64);
  if (lane == 0) wred[4 + w] = ssum;
  __syncthreads();
  ssum = wred[4] + wred[5] + wred[6] + wred[7];
  float inv = 1.0f / ssum;
  sa[tid] = e0 * inv;
  sa[tid + 256] = e1 * inv;
  __syncthreads();

  int d0 = ds * 64 + w * 16;
  const float4* hb = reinterpret_cast<const float4*>(h + (size_t)n * H2 * TT);
#pragma unroll 1
  for (int rr = 0; rr < 16; ++rr) {
    int d = d0 + rr;
    const float4* hr = hb + (size_t)d * (TT / 4);
    float4 a4 = hr[lane];
    float4 b4 = hr[64 + lane];
    int t0 = 4 * lane;
    float acc = a4.x * sa[t0] + a4.y * sa[t0 + 1] + a4.z * sa[t0 + 2] +
                a4.w * sa[t0 + 3] + b4.x * sa[256 + t0] +
                b4.y * sa[256 + t0 + 1] + b4.z * sa[256 + t0 + 2] +
                b4.w * sa[256 + t0 + 3];
#pragma unroll
    for (int off = 1; off <= 32; off <<= 1) acc += __shfl_xor(acc, off, 64);
    if (lane == 0) out[(size_t)n * H2 + d] = acc;
  }
}

// ---------------------------------------------------------------------------
extern "C" void kernel_launch(void* const* d_in, const int* in_sizes, int n_in,
                              void* d_out, int out_size, void* d_ws, size_t ws_size,
                              hipStream_t stream) {
  const float* h    = (const float*)d_in[0];  // (64, 1024, 512)
  const float* W    = (const float*)d_in[1];  // (1024, 1024)
  const float* bias = (const float*)d_in[2];  // (1024,)
  const float* u0   = (const float*)d_in[3];  // (1024,)
  float* out = (float*)d_out;                 // (64, 1024)

  float* wsf    = (float*)d_ws;
  float* norm2  = wsf;                          // 64
  float* scores = wsf + 64;                     // 64*512
  float* vbuf   = wsf + 64 + NSTEPS * TT;       // 64*1024
  unsigned* ctr = (unsigned*)(vbuf + (size_t)NSTEPS * H2);  // legacy pad slot
  float* after_ctr = (float*)(ctr + 16);        // pad
  size_t fixed_floats = (size_t)(after_ctr - wsf);
  _Float16* Wh  = (_Float16*)after_ctr;                       // 1M halfs
  _Float16* hhT = Wh + (size_t)H2 * H2;                       // 32M halfs
  size_t need = fixed_floats * 4 + (size_t)H2 * H2 * 2 +
                (size_t)NSTEPS * TT * H2 * 2;
  bool big = ws_size >= need;

  // zero norm2 + scores (atomically accumulated); poison vbuf for data-polling
  hipMemsetAsync(d_ws, 0, (size_t)(64 + NSTEPS * TT) * sizeof(float), stream);
  hipMemsetAsync(vbuf, 0xFF, (size_t)NSTEPS * H2 * sizeof(float), stream);

  // persistent recurrence, wait-free dataflow sync via poisoned vbuf
  // (cooperative launch only for the co-residency guarantee)
  {
    const float* Wp = W; const float* bp = bias; const float* up = u0;
    float* vp = vbuf; float* np = norm2;
    void* kargs[] = {&Wp, &bp, &up, &vp, &np};
    hipLaunchCooperativeKernel((void*)recur_kernel, dim3(RBLK), dim3(RTHR),
                               kargs, 0, stream);
  }

  if (big) {
    wconv_kernel<<<dim3(H2 * H2 / 1024), dim3(256), 0, stream>>>(W, Wh);
    transpose_h<<<dim3(16, 8, 64), dim3(256), 0, stream>>>(h, hhT);
    gemm2<<<dim3(2048), dim3(256), 0, stream>>>(Wh, hhT, bias, vbuf, norm2,
                                                scores);
  } else {
    gemm2<<<dim3(2048), dim3(256), 0, stream>>>(Wh, hhT, bias, vbuf, norm2,
                                                scores);
  }

  out_kernel<<<dim3(16, 64), dim3(256), 0, stream>>>(h, scores, out);

  (void)in_sizes; (void)n_in; (void)out_size; (void)ws_size;
}